// Round 1
// baseline (738.655 us; speedup 1.0000x reference)
//
#include <hip/hip_runtime.h>

// MoE top-2/8: routed bf16-MFMA grouped GEMMs.
// R1: correctness-first m97-style 128x128 GEMM structure.

#define N_TOK 8192
#define DIM   1024
#define HID   2048
#define NEXP  8
#define NK    (N_TOK * 2)
#define MAXT  136   // max row-tiles of 128 over all experts (sum ceil <= 135)

typedef __attribute__((ext_vector_type(8))) short short8;
typedef __attribute__((ext_vector_type(4))) float f32x4;

static __device__ __forceinline__ unsigned short f2bf(float f) {
  unsigned int u = __float_as_uint(f);
  u += 0x7fffu + ((u >> 16) & 1u);
  return (unsigned short)(u >> 16);
}

static __device__ __forceinline__ void glds16(const void* g, void* l) {
  __builtin_amdgcn_global_load_lds(
      (const __attribute__((address_space(1))) unsigned int*)g,
      (__attribute__((address_space(3))) unsigned int*)l, 16, 0, 0);
}

// ---- convert x (fp32) -> bf16, vectorized ----
__global__ __launch_bounds__(256) void cvt_x_k(const float4* __restrict__ src,
                                               ushort4* __restrict__ dst, int n4) {
  int i = blockIdx.x * 256 + threadIdx.x;
  if (i >= n4) return;
  float4 v = src[i];
  ushort4 o;
  o.x = f2bf(v.x); o.y = f2bf(v.y); o.z = f2bf(v.z); o.w = f2bf(v.w);
  dst[i] = o;
}

// ---- transpose-convert: src [E][R][C] fp32 -> dst [E][C][R] bf16 ----
__global__ __launch_bounds__(256) void transpose_cvt_k(const float* __restrict__ src,
                                                       unsigned short* __restrict__ dst,
                                                       int R, int C) {
  __shared__ float t[64][65];
  const float* s = src + (size_t)blockIdx.z * R * C;
  unsigned short* d = dst + (size_t)blockIdx.z * R * C;
  int c0 = blockIdx.x * 64, r0 = blockIdx.y * 64;
  int tid = threadIdx.x;
#pragma unroll
  for (int i = 0; i < 16; ++i) {
    int idx = i * 256 + tid;
    int r = idx >> 6, c = idx & 63;
    t[r][c] = s[(size_t)(r0 + r) * C + c0 + c];
  }
  __syncthreads();
#pragma unroll
  for (int i = 0; i < 16; ++i) {
    int idx = i * 256 + tid;
    int r = idx >> 6, c = idx & 63;   // r indexes C-dim, c indexes R-dim
    d[(size_t)(c0 + r) * R + r0 + c] = f2bf(t[c][r]);
  }
}

// ---- router: fp32 logits, top-2, softmax gates, per-expert counts ----
__global__ __launch_bounds__(256) void router_k(const float* __restrict__ x,
                                                const float* __restrict__ Wr,
                                                int* __restrict__ te, float* __restrict__ tg,
                                                int* __restrict__ cnt) {
  int n = blockIdx.x * 4 + (threadIdx.x >> 6);
  int lane = threadIdx.x & 63;
  float z[8];
#pragma unroll
  for (int e = 0; e < 8; ++e) z[e] = 0.f;
  const float* xr = x + (size_t)n * DIM;
#pragma unroll 4
  for (int i = 0; i < DIM / 64; ++i) {
    int d = lane + i * 64;
    float xv = xr[d];
    float4 w0 = *(const float4*)(Wr + (size_t)d * 8);
    float4 w1 = *(const float4*)(Wr + (size_t)d * 8 + 4);
    z[0] += xv * w0.x; z[1] += xv * w0.y; z[2] += xv * w0.z; z[3] += xv * w0.w;
    z[4] += xv * w1.x; z[5] += xv * w1.y; z[6] += xv * w1.z; z[7] += xv * w1.w;
  }
  for (int off = 32; off; off >>= 1)
#pragma unroll
    for (int e = 0; e < 8; ++e) z[e] += __shfl_down(z[e], off);
  if (lane == 0) {
    int e0 = 0; float v0 = z[0];
#pragma unroll
    for (int e = 1; e < 8; ++e) if (z[e] > v0) { v0 = z[e]; e0 = e; }
    int e1 = -1; float v1 = -3.4e38f;
#pragma unroll
    for (int e = 0; e < 8; ++e) if (e != e0 && z[e] > v1) { v1 = z[e]; e1 = e; }
    float r = expf(v1 - v0);          // <= 1
    float s0 = 1.f / (1.f + r);
    te[n * 2] = e0; te[n * 2 + 1] = e1;
    tg[n * 2] = s0; tg[n * 2 + 1] = r * s0;
    atomicAdd(&cnt[e0], 1);
    atomicAdd(&cnt[e1], 1);
  }
}

// ---- scan: offsets, cursors, row-tile offsets ----
__global__ void scan_k(const int* __restrict__ cnt, int* __restrict__ offs,
                       int* __restrict__ cur, int* __restrict__ tl) {
  if (threadIdx.x == 0) {
    int o = 0, t = 0;
    offs[0] = 0; tl[0] = 0;
    for (int e = 0; e < NEXP; ++e) {
      cur[e] = o;
      o += cnt[e];
      offs[e + 1] = o;
      t += (cnt[e] + 127) >> 7;
      tl[e + 1] = t;
    }
  }
}

// ---- scatter tokens into per-expert lists ----
__global__ __launch_bounds__(256) void scatter_k(const int* __restrict__ te,
                                                 const float* __restrict__ tg,
                                                 int* __restrict__ cur,
                                                 int* __restrict__ rows,
                                                 float* __restrict__ rowg) {
  int n = blockIdx.x * 256 + threadIdx.x;
  if (n >= N_TOK) return;
#pragma unroll
  for (int k = 0; k < 2; ++k) {
    int e = te[n * 2 + k];
    int pos = atomicAdd(&cur[e], 1);
    rows[pos] = n;
    rowg[pos] = tg[n * 2 + k];
  }
}

// ---- GEMM1: h = silu(Xg@W1a + b1a) * (Xg@W1b + b1b), 128 rows x 64 h-cols/block ----
__global__ __launch_bounds__(256) void gemm1_k(
    const unsigned short* __restrict__ xb,    // [N_TOK][DIM] bf16
    const unsigned short* __restrict__ w1t,   // [E][2H][DIM] bf16 (col-major source)
    const float* __restrict__ b1,             // [E][2H]
    unsigned short* __restrict__ hb,          // [NK][HID] bf16
    const int* __restrict__ rows,
    const int* __restrict__ offs,
    const int* __restrict__ tl) {
  __shared__ alignas(16) unsigned short As[128][32];
  __shared__ alignas(16) unsigned short Bs[128][32];
  int bt = blockIdx.x;
  if (bt >= tl[NEXP]) return;
  int e = 0;
  while (e < NEXP - 1 && bt >= tl[e + 1]) ++e;
  int rt = bt - tl[e];
  int base = offs[e];
  int cnt = offs[e + 1] - base;
  int row0 = rt * 128;
  int j0 = blockIdx.y * 64;

  int tid = threadIdx.x, wid = tid >> 6, lane = tid & 63;

  const unsigned short* asrc[2]; unsigned short* adst[2];
  const unsigned short* bsrc[2]; unsigned short* bdst[2];
#pragma unroll
  for (int s = 0; s < 2; ++s) {
    int i = wid * 2 + s;
    int r = row0 + i * 16 + (lane >> 2);
    int rr = r < cnt ? r : cnt - 1;
    int tok = rows[base + rr];
    asrc[s] = xb + (size_t)tok * DIM + (lane & 3) * 8;
    adst[s] = &As[i * 16][0];
    int c = i * 16 + (lane >> 2);
    int w1row = (c < 64) ? (j0 + c) : (HID + j0 + (c - 64));
    bsrc[s] = w1t + (size_t)e * 2 * HID * DIM + (size_t)w1row * DIM + (lane & 3) * 8;
    bdst[s] = &Bs[i * 16][0];
  }

  f32x4 acc[2][8];
#pragma unroll
  for (int m = 0; m < 2; ++m)
#pragma unroll
    for (int n = 0; n < 8; ++n) acc[m][n] = (f32x4){0.f, 0.f, 0.f, 0.f};

  for (int kk = 0; kk < DIM / 32; ++kk) {
    __syncthreads();
#pragma unroll
    for (int s = 0; s < 2; ++s) {
      glds16(asrc[s] + kk * 32, adst[s]);
      glds16(bsrc[s] + kk * 32, bdst[s]);
    }
    __syncthreads();
    short8 a[2], b[8];
    int kc = (lane >> 4) * 8;
#pragma unroll
    for (int m = 0; m < 2; ++m)
      a[m] = *(const short8*)&As[wid * 32 + m * 16 + (lane & 15)][kc];
#pragma unroll
    for (int n = 0; n < 8; ++n)
      b[n] = *(const short8*)&Bs[n * 16 + (lane & 15)][kc];
#pragma unroll
    for (int m = 0; m < 2; ++m)
#pragma unroll
      for (int n = 0; n < 8; ++n)
        acc[m][n] = __builtin_amdgcn_mfma_f32_16x16x32_bf16(a[m], b[n], acc[m][n], 0, 0, 0);
  }

  int coll = lane & 15, rowl = lane >> 4;
#pragma unroll
  for (int m = 0; m < 2; ++m)
#pragma unroll
    for (int n = 0; n < 4; ++n)
#pragma unroll
      for (int j = 0; j < 4; ++j) {
        int r = wid * 32 + m * 16 + rowl * 4 + j;
        int c = n * 16 + coll;   // 0..63
        float av = acc[m][n][j]     + b1[e * 2 * HID + j0 + c];
        float bv = acc[m][n + 4][j] + b1[e * 2 * HID + HID + j0 + c];
        float hv = av / (1.f + __expf(-av)) * bv;
        int gr = row0 + r;
        if (gr < cnt)
          hb[(size_t)(base + gr) * HID + j0 + c] = f2bf(hv);
      }
}

// ---- GEMM2: out[tok] += gate * (h @ W2 + b2), 128 rows x 128 cols/block ----
__global__ __launch_bounds__(256) void gemm2_k(
    const unsigned short* __restrict__ hb,    // [NK][HID] bf16
    const unsigned short* __restrict__ w2t,   // [E][DIM][HID] bf16
    const float* __restrict__ b2,             // [E][DIM]
    float* __restrict__ out,                  // [N_TOK][DIM] fp32
    const int* __restrict__ rows,
    const float* __restrict__ rowg,
    const int* __restrict__ offs,
    const int* __restrict__ tl) {
  __shared__ alignas(16) unsigned short As[128][32];
  __shared__ alignas(16) unsigned short Bs[128][32];
  int bt = blockIdx.x;
  if (bt >= tl[NEXP]) return;
  int e = 0;
  while (e < NEXP - 1 && bt >= tl[e + 1]) ++e;
  int rt = bt - tl[e];
  int base = offs[e];
  int cnt = offs[e + 1] - base;
  int row0 = rt * 128;
  int j0 = blockIdx.y * 128;

  int tid = threadIdx.x, wid = tid >> 6, lane = tid & 63;

  const unsigned short* asrc[2]; unsigned short* adst[2];
  const unsigned short* bsrc[2]; unsigned short* bdst[2];
#pragma unroll
  for (int s = 0; s < 2; ++s) {
    int i = wid * 2 + s;
    int r = row0 + i * 16 + (lane >> 2);
    int rr = r < cnt ? r : cnt - 1;
    asrc[s] = hb + (size_t)(base + rr) * HID + (lane & 3) * 8;
    adst[s] = &As[i * 16][0];
    int c = i * 16 + (lane >> 2);
    bsrc[s] = w2t + (size_t)e * DIM * HID + (size_t)(j0 + c) * HID + (lane & 3) * 8;
    bdst[s] = &Bs[i * 16][0];
  }

  f32x4 acc[2][8];
#pragma unroll
  for (int m = 0; m < 2; ++m)
#pragma unroll
    for (int n = 0; n < 8; ++n) acc[m][n] = (f32x4){0.f, 0.f, 0.f, 0.f};

  for (int kk = 0; kk < HID / 32; ++kk) {
    __syncthreads();
#pragma unroll
    for (int s = 0; s < 2; ++s) {
      glds16(asrc[s] + kk * 32, adst[s]);
      glds16(bsrc[s] + kk * 32, bdst[s]);
    }
    __syncthreads();
    short8 a[2], b[8];
    int kc = (lane >> 4) * 8;
#pragma unroll
    for (int m = 0; m < 2; ++m)
      a[m] = *(const short8*)&As[wid * 32 + m * 16 + (lane & 15)][kc];
#pragma unroll
    for (int n = 0; n < 8; ++n)
      b[n] = *(const short8*)&Bs[n * 16 + (lane & 15)][kc];
#pragma unroll
    for (int m = 0; m < 2; ++m)
#pragma unroll
      for (int n = 0; n < 8; ++n)
        acc[m][n] = __builtin_amdgcn_mfma_f32_16x16x32_bf16(a[m], b[n], acc[m][n], 0, 0, 0);
  }

  int coll = lane & 15, rowl = lane >> 4;
#pragma unroll
  for (int m = 0; m < 2; ++m)
#pragma unroll
    for (int j = 0; j < 4; ++j) {
      int r = wid * 32 + m * 16 + rowl * 4 + j;
      int gr = row0 + r;
      if (gr >= cnt) continue;
      int tok = rows[base + gr];
      float g = rowg[base + gr];
#pragma unroll
      for (int n = 0; n < 8; ++n) {
        int c = n * 16 + coll;
        float yv = acc[m][n][j] + b2[e * DIM + j0 + c];
        atomicAdd(&out[(size_t)tok * DIM + j0 + c], g * yv);
      }
    }
}

extern "C" void kernel_launch(void* const* d_in, const int* in_sizes, int n_in,
                              void* d_out, int out_size, void* d_ws, size_t ws_size,
                              hipStream_t stream) {
  (void)in_sizes; (void)n_in; (void)out_size;
  const float* x  = (const float*)d_in[0];
  const float* Wr = (const float*)d_in[1];
  const float* W1 = (const float*)d_in[2];
  const float* b1 = (const float*)d_in[3];
  const float* W2 = (const float*)d_in[4];
  const float* b2 = (const float*)d_in[5];
  float* out = (float*)d_out;
  char* ws = (char*)d_ws;

  const size_t o_xb   = 0;                                   // bf16 x
  const size_t o_w1t  = o_xb   + (size_t)N_TOK * DIM * 2;    // bf16 W1^T [E][4096][1024]
  const size_t o_w2t  = o_w1t  + (size_t)NEXP * 2 * HID * DIM * 2; // bf16 W2^T [E][1024][2048]
  const size_t o_hb   = o_w2t  + (size_t)NEXP * DIM * HID * 2;     // bf16 h [NK][2048]
  const size_t o_rows = o_hb   + (size_t)NK * HID * 2;
  const size_t o_rowg = o_rows + (size_t)NK * 4;
  const size_t o_te   = o_rowg + (size_t)NK * 4;
  const size_t o_tg   = o_te   + (size_t)NK * 4;
  const size_t o_cnt  = o_tg   + (size_t)NK * 4;
  const size_t o_offs = o_cnt  + 64;
  const size_t o_cur  = o_offs + 64;
  const size_t o_t1   = o_cur  + 64;
  const size_t need   = o_t1   + 64;
  if (ws_size < need) return;  // insufficient scratch -> loud failure (zero output)

  unsigned short* xb  = (unsigned short*)(ws + o_xb);
  unsigned short* w1t = (unsigned short*)(ws + o_w1t);
  unsigned short* w2t = (unsigned short*)(ws + o_w2t);
  unsigned short* hb  = (unsigned short*)(ws + o_hb);
  int*   rows = (int*)(ws + o_rows);
  float* rowg = (float*)(ws + o_rowg);
  int*   te   = (int*)(ws + o_te);
  float* tg   = (float*)(ws + o_tg);
  int*   cnt  = (int*)(ws + o_cnt);
  int*   offs = (int*)(ws + o_offs);
  int*   cur  = (int*)(ws + o_cur);
  int*   tl   = (int*)(ws + o_t1);

  hipMemsetAsync(out, 0, (size_t)N_TOK * DIM * sizeof(float), stream);
  hipMemsetAsync(cnt, 0, NEXP * sizeof(int), stream);

  cvt_x_k<<<(N_TOK * DIM / 4 + 255) / 256, 256, 0, stream>>>(
      (const float4*)x, (ushort4*)xb, N_TOK * DIM / 4);
  transpose_cvt_k<<<dim3(2 * HID / 64, DIM / 64, NEXP), 256, 0, stream>>>(W1, w1t, DIM, 2 * HID);
  transpose_cvt_k<<<dim3(DIM / 64, HID / 64, NEXP), 256, 0, stream>>>(W2, w2t, HID, DIM);
  router_k<<<N_TOK / 4, 256, 0, stream>>>(x, Wr, te, tg, cnt);
  scan_k<<<1, 64, 0, stream>>>(cnt, offs, cur, tl);
  scatter_k<<<N_TOK / 256, 256, 0, stream>>>(te, tg, cur, rows, rowg);
  gemm1_k<<<dim3(MAXT, 2 * HID / 128), 256, 0, stream>>>(xb, w1t, b1, hb, rows, offs, tl);
  gemm2_k<<<dim3(MAXT, DIM / 128), 256, 0, stream>>>(hb, w2t, b2, out, rows, rowg, offs, tl);
}

// Round 3
// 694.757 us; speedup vs baseline: 1.0632x; 1.0632x over previous
//
#include <hip/hip_runtime.h>

// MoE top-2/8: routed bf16-MFMA grouped GEMMs.
// R3: 256x256 8-phase schedule; fix tail vmcnt hole (drain when A-stage skipped).

#define N_TOK 8192
#define DIM   1024
#define HID   2048
#define NEXP  8
#define NK    (N_TOK * 2)
#define MAXT2 72    // max 256-row tiles over all experts (64 full + 8 partial)

typedef __attribute__((ext_vector_type(8))) short short8;
typedef __attribute__((ext_vector_type(4))) float f32x4;

#define BARX() __builtin_amdgcn_s_barrier()
#define FEN()  asm volatile("" ::: "memory")
#define VMW4() asm volatile("s_waitcnt vmcnt(4)" ::: "memory")
#define VMW0() asm volatile("s_waitcnt vmcnt(0)" ::: "memory")
#define PRIO(p) __builtin_amdgcn_s_setprio(p)

static __device__ __forceinline__ unsigned short f2bf(float f) {
  unsigned int u = __float_as_uint(f);
  u += 0x7fffu + ((u >> 16) & 1u);
  return (unsigned short)(u >> 16);
}

static __device__ __forceinline__ void glds16(const void* g, void* l) {
  __builtin_amdgcn_global_load_lds(
      (const __attribute__((address_space(1))) unsigned int*)g,
      (__attribute__((address_space(3))) unsigned int*)l, 16, 0, 0);
}

// ---- convert x (fp32) -> bf16, vectorized ----
__global__ __launch_bounds__(256) void cvt_x_k(const float4* __restrict__ src,
                                               ushort4* __restrict__ dst, int n4) {
  int i = blockIdx.x * 256 + threadIdx.x;
  if (i >= n4) return;
  float4 v = src[i];
  ushort4 o;
  o.x = f2bf(v.x); o.y = f2bf(v.y); o.z = f2bf(v.z); o.w = f2bf(v.w);
  dst[i] = o;
}

// ---- transpose-convert: src [E][R][C] fp32 -> dst [E][C][R] bf16 ----
__global__ __launch_bounds__(256) void transpose_cvt_k(const float* __restrict__ src,
                                                       unsigned short* __restrict__ dst,
                                                       int R, int C) {
  __shared__ float t[64][65];
  const float* s = src + (size_t)blockIdx.z * R * C;
  unsigned short* d = dst + (size_t)blockIdx.z * R * C;
  int c0 = blockIdx.x * 64, r0 = blockIdx.y * 64;
  int tid = threadIdx.x;
#pragma unroll
  for (int i = 0; i < 16; ++i) {
    int idx = i * 256 + tid;
    int r = idx >> 6, c = idx & 63;
    t[r][c] = s[(size_t)(r0 + r) * C + c0 + c];
  }
  __syncthreads();
#pragma unroll
  for (int i = 0; i < 16; ++i) {
    int idx = i * 256 + tid;
    int r = idx >> 6, c = idx & 63;
    d[(size_t)(c0 + r) * R + r0 + c] = f2bf(t[c][r]);
  }
}

// ---- router: fp32 logits, top-2, softmax gates, per-expert counts ----
__global__ __launch_bounds__(256) void router_k(const float* __restrict__ x,
                                                const float* __restrict__ Wr,
                                                int* __restrict__ te, float* __restrict__ tg,
                                                int* __restrict__ cnt) {
  int n = blockIdx.x * 4 + (threadIdx.x >> 6);
  int lane = threadIdx.x & 63;
  float z[8];
#pragma unroll
  for (int e = 0; e < 8; ++e) z[e] = 0.f;
  const float* xr = x + (size_t)n * DIM;
#pragma unroll 4
  for (int i = 0; i < DIM / 64; ++i) {
    int d = lane + i * 64;
    float xv = xr[d];
    float4 w0 = *(const float4*)(Wr + (size_t)d * 8);
    float4 w1 = *(const float4*)(Wr + (size_t)d * 8 + 4);
    z[0] += xv * w0.x; z[1] += xv * w0.y; z[2] += xv * w0.z; z[3] += xv * w0.w;
    z[4] += xv * w1.x; z[5] += xv * w1.y; z[6] += xv * w1.z; z[7] += xv * w1.w;
  }
  for (int off = 32; off; off >>= 1)
#pragma unroll
    for (int e = 0; e < 8; ++e) z[e] += __shfl_down(z[e], off);
  if (lane == 0) {
    int e0 = 0; float v0 = z[0];
#pragma unroll
    for (int e = 1; e < 8; ++e) if (z[e] > v0) { v0 = z[e]; e0 = e; }
    int e1 = -1; float v1 = -3.4e38f;
#pragma unroll
    for (int e = 0; e < 8; ++e) if (e != e0 && z[e] > v1) { v1 = z[e]; e1 = e; }
    float r = expf(v1 - v0);
    float s0 = 1.f / (1.f + r);
    te[n * 2] = e0; te[n * 2 + 1] = e1;
    tg[n * 2] = s0; tg[n * 2 + 1] = r * s0;
    atomicAdd(&cnt[e0], 1);
    atomicAdd(&cnt[e1], 1);
  }
}

// ---- scan: offsets, cursors, 256-row tile offsets ----
__global__ void scan_k(const int* __restrict__ cnt, int* __restrict__ offs,
                       int* __restrict__ cur, int* __restrict__ tl) {
  if (threadIdx.x == 0) {
    int o = 0, t = 0;
    offs[0] = 0; tl[0] = 0;
    for (int e = 0; e < NEXP; ++e) {
      cur[e] = o;
      o += cnt[e];
      offs[e + 1] = o;
      t += (cnt[e] + 255) >> 8;
      tl[e + 1] = t;
    }
  }
}

// ---- scatter tokens into per-expert lists ----
__global__ __launch_bounds__(256) void scatter_k(const int* __restrict__ te,
                                                 const float* __restrict__ tg,
                                                 int* __restrict__ cur,
                                                 int* __restrict__ rows,
                                                 float* __restrict__ rowg) {
  int n = blockIdx.x * 256 + threadIdx.x;
  if (n >= N_TOK) return;
#pragma unroll
  for (int k = 0; k < 2; ++k) {
    int e = te[n * 2 + k];
    int pos = atomicAdd(&cur[e], 1);
    rows[pos] = n;
    rowg[pos] = tg[n * 2 + k];
  }
}

// ================= 8-phase 256x256 grouped GEMM =================
// GID=0: h = swiglu(Xg @ W1[e] + b1[e]); A = gathered xb rows (K=1024),
//        B rows interleaved (a/b col pairs), N-tile = 256 B-rows = 128 h-cols.
// GID=1: out += gate * (h @ W2[e] + b2[e]); A = contiguous hb rows (K=2048),
//        N-tile = 256 out-cols.
template <int GID>
__global__ __launch_bounds__(512, 2) void moe_gemm8p(
    const unsigned short* __restrict__ Asrc,   // xb or hb
    const unsigned short* __restrict__ Wt,     // w1t [E][4096][1024] or w2t [E][1024][2048]
    const float* __restrict__ bias,            // b1 [E][4096] or b2 [E][1024]
    unsigned short* __restrict__ hb,           // GID0 output
    float* __restrict__ out,                   // GID1 output
    const int* __restrict__ rows,
    const float* __restrict__ rowg,
    const int* __restrict__ offs,
    const int* __restrict__ tl) {
  constexpr int KD = (GID == 0) ? DIM : HID;   // K extent
  constexpr int NT = KD / 64;                  // K-tiles
  // 4 slabs of 32KB: A-even, A-odd, B-even, B-odd  (elements of ushort)
  __shared__ unsigned short smem[4 * 16384];

  int bt = blockIdx.x;
  if (bt >= tl[NEXP]) return;
  int e = 0;
  while (e < NEXP - 1 && bt >= tl[e + 1]) ++e;
  int rt = bt - tl[e];
  int base = offs[e];
  int cntE = offs[e + 1] - base;
  int row0 = rt * 256;

  int tid = threadIdx.x, lane = tid & 63, w = tid >> 6;
  int wr = w >> 2, wc = w & 3;

  // ---------- staging sources (pre-swizzled global addresses, rule 21) ----------
  // lane l stages LDS linear slot: row = wbase + s*8 + (l>>3), slot16B = l&7.
  // logical k-group g = slot ^ (row&7) = (l&7) ^ (l>>3).
  int g8 = (((lane & 7) ^ (lane >> 3)) * 8);   // element offset in 64-col K slab
  const unsigned short* aS[4];
  const unsigned short* bS[4];
#pragma unroll
  for (int s = 0; s < 4; ++s) {
    int r = w * 32 + s * 8 + (lane >> 3);      // 0..255 within tile
    int rr = row0 + r; rr = rr < cntE ? rr : cntE - 1;
    if (GID == 0) {
      int tok = rows[base + rr];
      aS[s] = Asrc + (size_t)tok * DIM + g8;
    } else {
      aS[s] = Asrc + (size_t)(base + rr) * HID + g8;
    }
    if (GID == 0) {
      int j0h = blockIdx.y * 128;
      int hcol = j0h + (r >> 5) * 16 + (r & 15);
      int w1row = hcol + ((r >> 4) & 1) * HID;          // +HID for b-half
      bS[s] = Wt + ((size_t)e * 2 * HID + w1row) * DIM + g8;
    } else {
      int j0 = blockIdx.y * 256;
      bS[s] = Wt + ((size_t)e * DIM + (j0 + r)) * HID + g8;
    }
  }
  const int dOff = w * 2048;                    // wave-uniform LDS dst (elements)

  auto stgA = [&](int t) {
    if (t < NT) {
#pragma unroll
      for (int s = 0; s < 4; ++s)
        glds16(aS[s] + (size_t)t * 64, smem + (t & 1) * 16384 + dOff + s * 512);
    }
  };
  auto stgB = [&](int t) {
    if (t < NT) {
#pragma unroll
      for (int s = 0; s < 4; ++s)
        glds16(bS[s] + (size_t)t * 64, smem + 32768 + (t & 1) * 16384 + dOff + s * 512);
    }
  };

  // ---------- ds_read offsets (elements), swizzle matches staging ----------
  int arow = wr * 128 + (lane & 15);
  int brow = wc * 64 + (lane & 15);
  int kg = lane >> 4, sx = lane & 7;
  unsigned aoff0 = (unsigned)(arow * 64 + ((kg ^ sx) * 8));
  unsigned aoff1 = (unsigned)(arow * 64 + (((4 + kg) ^ sx) * 8));
  unsigned boff0 = (unsigned)(brow * 64 + ((kg ^ sx) * 8));
  unsigned boff1 = (unsigned)(brow * 64 + (((4 + kg) ^ sx) * 8));

  f32x4 acc[8][4];
#pragma unroll
  for (int m = 0; m < 8; ++m)
#pragma unroll
    for (int n = 0; n < 4; ++n) acc[m][n] = (f32x4){0.f, 0.f, 0.f, 0.f};

  // ---------- prologue: stage A0,B0,A1; land A0,B0 ----------
  stgA(0); stgB(0); stgA(1);
  VMW4(); FEN(); BARX(); FEN();

  // ---------- main loop: 2 K-tiles per iter, 8 phases ----------
  for (int it = 0; it < NT / 2; ++it) {
    int t0 = 2 * it;
#pragma unroll
    for (int h = 0; h < 2; ++h) {
      int tt = t0 + h;
      int stB = tt + 1;            // ph-A stage
      int stA = tt + 2;            // ph-D stage
      unsigned Ab = (unsigned)((tt & 1) * 16384);
      unsigned Bb = 32768u + Ab;
      short8 a[8], b[4];
      // ---- PH-A: reads ks0, stage B(tt+1) ----
#pragma unroll
      for (int m = 0; m < 8; ++m) a[m] = *(const short8*)(smem + Ab + aoff0 + m * 1024);
#pragma unroll
      for (int n = 0; n < 4; ++n) b[n] = *(const short8*)(smem + Bb + boff0 + n * 1024);
      stgB(stB);
      FEN(); BARX(); FEN();
      PRIO(1);
#pragma unroll
      for (int m = 0; m < 4; ++m)
#pragma unroll
        for (int n = 0; n < 4; ++n)
          acc[m][n] = __builtin_amdgcn_mfma_f32_16x16x32_bf16(a[m], b[n], acc[m][n], 0, 0, 0);
      PRIO(0);
      FEN(); BARX(); FEN();
      // ---- PH-B: MFMA ks0 m4-7 ----
      PRIO(1);
#pragma unroll
      for (int m = 4; m < 8; ++m)
#pragma unroll
        for (int n = 0; n < 4; ++n)
          acc[m][n] = __builtin_amdgcn_mfma_f32_16x16x32_bf16(a[m], b[n], acc[m][n], 0, 0, 0);
      PRIO(0);
      FEN(); BARX(); FEN();
      // ---- PH-C: reads ks1 ----
#pragma unroll
      for (int m = 0; m < 8; ++m) a[m] = *(const short8*)(smem + Ab + aoff1 + m * 1024);
#pragma unroll
      for (int n = 0; n < 4; ++n) b[n] = *(const short8*)(smem + Bb + boff1 + n * 1024);
      FEN(); BARX(); FEN();
      PRIO(1);
#pragma unroll
      for (int m = 0; m < 4; ++m)
#pragma unroll
        for (int n = 0; n < 4; ++n)
          acc[m][n] = __builtin_amdgcn_mfma_f32_16x16x32_bf16(a[m], b[n], acc[m][n], 0, 0, 0);
      PRIO(0);
      FEN(); BARX(); FEN();
      // ---- PH-D: stage A(tt+2), guard, MFMA ks1 m4-7 ----
      stgA(stA);
      // Counted wait only while the A-stage was actually issued; otherwise the
      // queue holds just {A(NT-1),B(NT-1)} and vmcnt(4) would leave B un-landed
      // for the final tile's reads (the R2 tail race). Drain instead.
      if (stA < NT) { VMW4(); } else { VMW0(); }
      FEN(); BARX(); FEN();
      PRIO(1);
#pragma unroll
      for (int m = 4; m < 8; ++m)
#pragma unroll
        for (int n = 0; n < 4; ++n)
          acc[m][n] = __builtin_amdgcn_mfma_f32_16x16x32_bf16(a[m], b[n], acc[m][n], 0, 0, 0);
      PRIO(0);
      FEN(); BARX(); FEN();
    }
  }

  // ---------- epilogue ----------
  int rowl = lane >> 4, coll = lane & 15;
  if (GID == 0) {
    int j0h = blockIdx.y * 128;
#pragma unroll
    for (int pair = 0; pair < 2; ++pair) {
      int hcol = j0h + (2 * wc + pair) * 16 + coll;
      float ba = bias[e * 2 * HID + hcol];
      float bb = bias[e * 2 * HID + HID + hcol];
#pragma unroll
      for (int m = 0; m < 8; ++m)
#pragma unroll
        for (int j = 0; j < 4; ++j) {
          int grow = row0 + wr * 128 + m * 16 + rowl * 4 + j;
          if (grow < cntE) {
            float av = acc[m][2 * pair][j] + ba;
            float bv = acc[m][2 * pair + 1][j] + bb;
            float hv = av / (1.f + __expf(-av)) * bv;
            hb[(size_t)(base + grow) * HID + hcol] = f2bf(hv);
          }
        }
    }
  } else {
    int j0 = blockIdx.y * 256;
    float bv[4];
#pragma unroll
    for (int n = 0; n < 4; ++n) bv[n] = bias[e * DIM + j0 + wc * 64 + n * 16 + coll];
#pragma unroll
    for (int m = 0; m < 8; ++m)
#pragma unroll
      for (int j = 0; j < 4; ++j) {
        int grow = row0 + wr * 128 + m * 16 + rowl * 4 + j;
        if (grow < cntE) {
          int tok = rows[base + grow];
          float g = rowg[base + grow];
#pragma unroll
          for (int n = 0; n < 4; ++n) {
            int col = j0 + wc * 64 + n * 16 + coll;
            atomicAdd(&out[(size_t)tok * DIM + col], g * (acc[m][n][j] + bv[n]));
          }
        }
      }
  }
}

extern "C" void kernel_launch(void* const* d_in, const int* in_sizes, int n_in,
                              void* d_out, int out_size, void* d_ws, size_t ws_size,
                              hipStream_t stream) {
  (void)in_sizes; (void)n_in; (void)out_size;
  const float* x  = (const float*)d_in[0];
  const float* Wr = (const float*)d_in[1];
  const float* W1 = (const float*)d_in[2];
  const float* b1 = (const float*)d_in[3];
  const float* W2 = (const float*)d_in[4];
  const float* b2 = (const float*)d_in[5];
  float* out = (float*)d_out;
  char* ws = (char*)d_ws;

  const size_t o_xb   = 0;
  const size_t o_w1t  = o_xb   + (size_t)N_TOK * DIM * 2;
  const size_t o_w2t  = o_w1t  + (size_t)NEXP * 2 * HID * DIM * 2;
  const size_t o_hb   = o_w2t  + (size_t)NEXP * DIM * HID * 2;
  const size_t o_rows = o_hb   + (size_t)NK * HID * 2;
  const size_t o_rowg = o_rows + (size_t)NK * 4;
  const size_t o_te   = o_rowg + (size_t)NK * 4;
  const size_t o_tg   = o_te   + (size_t)NK * 4;
  const size_t o_cnt  = o_tg   + (size_t)NK * 4;
  const size_t o_offs = o_cnt  + 64;
  const size_t o_cur  = o_offs + 64;
  const size_t o_t1   = o_cur  + 64;
  const size_t need   = o_t1   + 64;
  if (ws_size < need) return;

  unsigned short* xb  = (unsigned short*)(ws + o_xb);
  unsigned short* w1t = (unsigned short*)(ws + o_w1t);
  unsigned short* w2t = (unsigned short*)(ws + o_w2t);
  unsigned short* hb  = (unsigned short*)(ws + o_hb);
  int*   rows = (int*)(ws + o_rows);
  float* rowg = (float*)(ws + o_rowg);
  int*   te   = (int*)(ws + o_te);
  float* tg   = (float*)(ws + o_tg);
  int*   cnt  = (int*)(ws + o_cnt);
  int*   offs = (int*)(ws + o_offs);
  int*   cur  = (int*)(ws + o_cur);
  int*   tl   = (int*)(ws + o_t1);

  hipMemsetAsync(out, 0, (size_t)N_TOK * DIM * sizeof(float), stream);
  hipMemsetAsync(cnt, 0, NEXP * sizeof(int), stream);

  cvt_x_k<<<(N_TOK * DIM / 4 + 255) / 256, 256, 0, stream>>>(
      (const float4*)x, (ushort4*)xb, N_TOK * DIM / 4);
  transpose_cvt_k<<<dim3(2 * HID / 64, DIM / 64, NEXP), 256, 0, stream>>>(W1, w1t, DIM, 2 * HID);
  transpose_cvt_k<<<dim3(DIM / 64, HID / 64, NEXP), 256, 0, stream>>>(W2, w2t, HID, DIM);
  router_k<<<N_TOK / 4, 256, 0, stream>>>(x, Wr, te, tg, cnt);
  scan_k<<<1, 64, 0, stream>>>(cnt, offs, cur, tl);
  scatter_k<<<N_TOK / 256, 256, 0, stream>>>(te, tg, cur, rows, rowg);
  moe_gemm8p<0><<<dim3(MAXT2, HID / 128), 512, 0, stream>>>(
      xb, w1t, b1, hb, nullptr, rows, rowg, offs, tl);
  moe_gemm8p<1><<<dim3(MAXT2, DIM / 256), 512, 0, stream>>>(
      hb, w2t, b2, nullptr, out, rows, rowg, offs, tl);
}

// Round 4
// 681.898 us; speedup vs baseline: 1.0832x; 1.0189x over previous
//
#include <hip/hip_runtime.h>

// MoE top-2/8: routed bf16-MFMA grouped GEMMs.
// R4: true per-phase interleave (ds_read || one half-tile stage || 16 MFMA per
// phase), counted vmcnt(4) twice per 2 K-tiles placed guard-before-barrier.

#define N_TOK 8192
#define DIM   1024
#define HID   2048
#define NEXP  8
#define NK    (N_TOK * 2)
#define MAXT2 72    // max 256-row tiles over all experts (64 full + 8 partial)

typedef __attribute__((ext_vector_type(8))) short short8;
typedef __attribute__((ext_vector_type(4))) float f32x4;

#define BARX() __builtin_amdgcn_s_barrier()
#define FEN()  asm volatile("" ::: "memory")
#define VMW4() asm volatile("s_waitcnt vmcnt(4)" ::: "memory")
#define VMW0() asm volatile("s_waitcnt vmcnt(0)" ::: "memory")
#define PRIO(p) __builtin_amdgcn_s_setprio(p)

static __device__ __forceinline__ unsigned short f2bf(float f) {
  unsigned int u = __float_as_uint(f);
  u += 0x7fffu + ((u >> 16) & 1u);
  return (unsigned short)(u >> 16);
}

static __device__ __forceinline__ void glds16(const void* g, void* l) {
  __builtin_amdgcn_global_load_lds(
      (const __attribute__((address_space(1))) unsigned int*)g,
      (__attribute__((address_space(3))) unsigned int*)l, 16, 0, 0);
}

// ---- convert x (fp32) -> bf16, vectorized ----
__global__ __launch_bounds__(256) void cvt_x_k(const float4* __restrict__ src,
                                               ushort4* __restrict__ dst, int n4) {
  int i = blockIdx.x * 256 + threadIdx.x;
  if (i >= n4) return;
  float4 v = src[i];
  ushort4 o;
  o.x = f2bf(v.x); o.y = f2bf(v.y); o.z = f2bf(v.z); o.w = f2bf(v.w);
  dst[i] = o;
}

// ---- transpose-convert: src [E][R][C] fp32 -> dst [E][C][R] bf16 ----
__global__ __launch_bounds__(256) void transpose_cvt_k(const float* __restrict__ src,
                                                       unsigned short* __restrict__ dst,
                                                       int R, int C) {
  __shared__ float t[64][65];
  const float* s = src + (size_t)blockIdx.z * R * C;
  unsigned short* d = dst + (size_t)blockIdx.z * R * C;
  int c0 = blockIdx.x * 64, r0 = blockIdx.y * 64;
  int tid = threadIdx.x;
#pragma unroll
  for (int i = 0; i < 16; ++i) {
    int idx = i * 256 + tid;
    int r = idx >> 6, c = idx & 63;
    t[r][c] = s[(size_t)(r0 + r) * C + c0 + c];
  }
  __syncthreads();
#pragma unroll
  for (int i = 0; i < 16; ++i) {
    int idx = i * 256 + tid;
    int r = idx >> 6, c = idx & 63;
    d[(size_t)(c0 + r) * R + r0 + c] = f2bf(t[c][r]);
  }
}

// ---- router: fp32 logits, top-2, softmax gates, per-expert counts ----
__global__ __launch_bounds__(256) void router_k(const float* __restrict__ x,
                                                const float* __restrict__ Wr,
                                                int* __restrict__ te, float* __restrict__ tg,
                                                int* __restrict__ cnt) {
  int n = blockIdx.x * 4 + (threadIdx.x >> 6);
  int lane = threadIdx.x & 63;
  float z[8];
#pragma unroll
  for (int e = 0; e < 8; ++e) z[e] = 0.f;
  const float* xr = x + (size_t)n * DIM;
#pragma unroll 4
  for (int i = 0; i < DIM / 64; ++i) {
    int d = lane + i * 64;
    float xv = xr[d];
    float4 w0 = *(const float4*)(Wr + (size_t)d * 8);
    float4 w1 = *(const float4*)(Wr + (size_t)d * 8 + 4);
    z[0] += xv * w0.x; z[1] += xv * w0.y; z[2] += xv * w0.z; z[3] += xv * w0.w;
    z[4] += xv * w1.x; z[5] += xv * w1.y; z[6] += xv * w1.z; z[7] += xv * w1.w;
  }
  for (int off = 32; off; off >>= 1)
#pragma unroll
    for (int e = 0; e < 8; ++e) z[e] += __shfl_down(z[e], off);
  if (lane == 0) {
    int e0 = 0; float v0 = z[0];
#pragma unroll
    for (int e = 1; e < 8; ++e) if (z[e] > v0) { v0 = z[e]; e0 = e; }
    int e1 = -1; float v1 = -3.4e38f;
#pragma unroll
    for (int e = 0; e < 8; ++e) if (e != e0 && z[e] > v1) { v1 = z[e]; e1 = e; }
    float r = expf(v1 - v0);
    float s0 = 1.f / (1.f + r);
    te[n * 2] = e0; te[n * 2 + 1] = e1;
    tg[n * 2] = s0; tg[n * 2 + 1] = r * s0;
    atomicAdd(&cnt[e0], 1);
    atomicAdd(&cnt[e1], 1);
  }
}

// ---- scan: offsets, cursors, 256-row tile offsets ----
__global__ void scan_k(const int* __restrict__ cnt, int* __restrict__ offs,
                       int* __restrict__ cur, int* __restrict__ tl) {
  if (threadIdx.x == 0) {
    int o = 0, t = 0;
    offs[0] = 0; tl[0] = 0;
    for (int e = 0; e < NEXP; ++e) {
      cur[e] = o;
      o += cnt[e];
      offs[e + 1] = o;
      t += (cnt[e] + 255) >> 8;
      tl[e + 1] = t;
    }
  }
}

// ---- scatter tokens into per-expert lists ----
__global__ __launch_bounds__(256) void scatter_k(const int* __restrict__ te,
                                                 const float* __restrict__ tg,
                                                 int* __restrict__ cur,
                                                 int* __restrict__ rows,
                                                 float* __restrict__ rowg) {
  int n = blockIdx.x * 256 + threadIdx.x;
  if (n >= N_TOK) return;
#pragma unroll
  for (int k = 0; k < 2; ++k) {
    int e = te[n * 2 + k];
    int pos = atomicAdd(&cur[e], 1);
    rows[pos] = n;
    rowg[pos] = tg[n * 2 + k];
  }
}

// ================= 8-phase 256x256 grouped GEMM (per-phase interleave) ======
// Per iteration (2 K-tiles T,T+1; even/odd LDS slabs static):
//  P0: read a[h0],b[v0] of T   | stage B(T+1).h0 | MFMA m0-3 x n0-1
//  P1: read b[v1]              | stage B(T+1).h1 | MFMA m0-3 x n2-3
//  P2: read a[h1]              | stage A(T+2).q0 | MFMA m4-7 x n2-3
//  P3: (no reads)              | stage A(T+2).q1 | MFMA m4-7 x n0-1 | vmcnt(4)
//  P4-P7: same on T+1, staging B(T+2), A(T+3)    | vmcnt(4) at P7
// A stage "quarters" q0/q1 = rows with bit6==0 / bit6==1 (matches the order
// the m-halves release LDS). Guards sit just before the closing barrier so the
// following barrier makes them block-wide.
template <int GID>
__global__ __launch_bounds__(512, 2) void moe_gemm8p(
    const unsigned short* __restrict__ Asrc,   // xb or hb
    const unsigned short* __restrict__ Wt,     // w1t [E][4096][1024] or w2t [E][1024][2048]
    const float* __restrict__ bias,            // b1 [E][4096] or b2 [E][1024]
    unsigned short* __restrict__ hb,           // GID0 output
    float* __restrict__ out,                   // GID1 output
    const int* __restrict__ rows,
    const float* __restrict__ rowg,
    const int* __restrict__ offs,
    const int* __restrict__ tl) {
  constexpr int KD = (GID == 0) ? DIM : HID;
  constexpr int NT = KD / 64;
  // slabs (elements): A-even 0, A-odd 16384, B-even 32768, B-odd 49152
  __shared__ unsigned short smem[4 * 16384];

  int bt = blockIdx.x;
  if (bt >= tl[NEXP]) return;
  int e = 0;
  while (e < NEXP - 1 && bt >= tl[e + 1]) ++e;
  int rt = bt - tl[e];
  int base = offs[e];
  int cntE = offs[e + 1] - base;
  int row0 = rt * 256;

  int tid = threadIdx.x, lane = tid & 63, w = tid >> 6;
  int wr = w >> 2, wc = w & 3;

  // ---------- staging sources/dsts: 2 halves x 2 slots, 2 glds each ----------
  int g8 = (((lane & 7) ^ ((lane >> 3) & 7)) * 8);  // pre-swizzled k-group
  const unsigned short* aP[2][2];
  const unsigned short* bP[2][2];
  int aD[2][2], bD[2][2];
#pragma unroll
  for (int hf = 0; hf < 2; ++hf)
#pragma unroll
    for (int s = 0; s < 2; ++s) {
      int q0 = w * 16 + s * 8;
      // A half hf covers rows with bit6==hf: {0-63,128-191} or {64-127,192-255}
      int rbA = hf == 0 ? (q0 < 64 ? q0 : q0 + 64) : (q0 < 64 ? q0 + 64 : q0 + 128);
      int rA = rbA + (lane >> 3);
      int rr = row0 + rA; rr = rr < cntE ? rr : cntE - 1;
      if (GID == 0) {
        int tok = rows[base + rr];
        aP[hf][s] = Asrc + (size_t)tok * DIM + g8;
      } else {
        aP[hf][s] = Asrc + (size_t)(base + rr) * HID + g8;
      }
      aD[hf][s] = rbA * 64;
      int rB = hf * 128 + q0 + (lane >> 3);
      if (GID == 0) {
        int j0h = blockIdx.y * 128;
        int hcol = j0h + (rB >> 5) * 16 + (rB & 15);
        int w1row = hcol + ((rB >> 4) & 1) * HID;   // +HID for b-half of swiGLU
        bP[hf][s] = Wt + ((size_t)e * 2 * HID + w1row) * DIM + g8;
      } else {
        int j0 = blockIdx.y * 256;
        bP[hf][s] = Wt + ((size_t)e * DIM + (j0 + rB)) * HID + g8;
      }
      bD[hf][s] = (hf * 128 + q0) * 64;
    }

  auto stA = [&](int t, int hf) {
    if (t < NT) {
#pragma unroll
      for (int s = 0; s < 2; ++s)
        glds16(aP[hf][s] + (size_t)t * 64, smem + (t & 1) * 16384 + aD[hf][s]);
    }
  };
  auto stB = [&](int t, int hf) {
    if (t < NT) {
#pragma unroll
      for (int s = 0; s < 2; ++s)
        glds16(bP[hf][s] + (size_t)t * 64, smem + 32768 + (t & 1) * 16384 + bD[hf][s]);
    }
  };

  // ---------- ds_read offsets (elements), swizzle matches staging ----------
  int arow = wr * 128 + (lane & 15);
  int brow = wc * 64 + (lane & 15);
  int kg = lane >> 4, sx = lane & 7;
  unsigned aoffs[2] = {(unsigned)(arow * 64 + ((kg ^ sx) * 8)),
                       (unsigned)(arow * 64 + (((4 + kg) ^ sx) * 8))};
  unsigned boffs[2] = {(unsigned)(brow * 64 + ((kg ^ sx) * 8)),
                       (unsigned)(brow * 64 + (((4 + kg) ^ sx) * 8))};

  f32x4 acc[8][4];
#pragma unroll
  for (int m = 0; m < 8; ++m)
#pragma unroll
    for (int n = 0; n < 4; ++n) acc[m][n] = (f32x4){0.f, 0.f, 0.f, 0.f};

  short8 a[2][4], b[2][4];

#define MFMA_Q(MB, NB)                                                        \
  PRIO(1);                                                                    \
  _Pragma("unroll") for (int ks = 0; ks < 2; ++ks)                            \
  _Pragma("unroll") for (int m = 0; m < 4; ++m)                               \
  _Pragma("unroll") for (int n = 0; n < 2; ++n)                               \
    acc[(MB) + m][(NB) + n] = __builtin_amdgcn_mfma_f32_16x16x32_bf16(        \
        a[ks][m], b[ks][(NB) + n], acc[(MB) + m][(NB) + n], 0, 0, 0);         \
  PRIO(0)

  // ---------- prologue: A0, B0, A1 halves; land A0,B0 ----------
  stA(0, 0); stA(0, 1); stB(0, 0); stB(0, 1); stA(1, 0); stA(1, 1);
  VMW4(); FEN(); BARX(); FEN();

  for (int it = 0; it < NT / 2; ++it) {
    int T = 2 * it;
    bool notlast = (it < NT / 2 - 1);
#pragma unroll
    for (int half = 0; half < 2; ++half) {
      unsigned Ab = half ? 16384u : 0u;
      unsigned Bb = 32768u + Ab;
      int Tn = T + half;
      // ---- P0/P4: a[h0], b[v0]; stage B(Tn+1).h0 ----
#pragma unroll
      for (int ks = 0; ks < 2; ++ks) {
#pragma unroll
        for (int m = 0; m < 4; ++m)
          a[ks][m] = *(const short8*)(smem + Ab + aoffs[ks] + m * 1024);
#pragma unroll
        for (int n = 0; n < 2; ++n)
          b[ks][n] = *(const short8*)(smem + Bb + boffs[ks] + n * 1024);
      }
      stB(Tn + 1, 0);
      FEN(); BARX(); FEN();
      MFMA_Q(0, 0);
      FEN(); BARX(); FEN();
      // ---- P1/P5: b[v1]; stage B(Tn+1).h1 ----
#pragma unroll
      for (int ks = 0; ks < 2; ++ks)
#pragma unroll
        for (int n = 2; n < 4; ++n)
          b[ks][n] = *(const short8*)(smem + Bb + boffs[ks] + n * 1024);
      stB(Tn + 1, 1);
      FEN(); BARX(); FEN();
      MFMA_Q(0, 2);
      FEN(); BARX(); FEN();
      // ---- P2/P6: a[h1]; stage A(Tn+2).q0 ----
#pragma unroll
      for (int ks = 0; ks < 2; ++ks)
#pragma unroll
        for (int m = 0; m < 4; ++m)
          a[ks][m] = *(const short8*)(smem + Ab + aoffs[ks] + (4 + m) * 1024);
      stA(Tn + 2, 0);
      FEN(); BARX(); FEN();
      MFMA_Q(4, 2);
      FEN(); BARX(); FEN();
      // ---- P3/P7: stage A(Tn+2).q1; MFMA; guard-before-barrier ----
      stA(Tn + 2, 1);
      FEN(); BARX(); FEN();
      MFMA_Q(4, 0);
      if (half == 0) {
        if (notlast) { VMW4(); } else { VMW0(); }
      } else {
        VMW4();
      }
      FEN(); BARX(); FEN();
    }
  }
#undef MFMA_Q

  // ---------- epilogue ----------
  int rowl = lane >> 4, coll = lane & 15;
  if (GID == 0) {
    int j0h = blockIdx.y * 128;
#pragma unroll
    for (int pair = 0; pair < 2; ++pair) {
      int hcol = j0h + (2 * wc + pair) * 16 + coll;
      float ba = bias[e * 2 * HID + hcol];
      float bb = bias[e * 2 * HID + HID + hcol];
#pragma unroll
      for (int m = 0; m < 8; ++m)
#pragma unroll
        for (int j = 0; j < 4; ++j) {
          int grow = row0 + wr * 128 + m * 16 + rowl * 4 + j;
          if (grow < cntE) {
            float av = acc[m][2 * pair][j] + ba;
            float bv = acc[m][2 * pair + 1][j] + bb;
            float hv = av / (1.f + __expf(-av)) * bv;
            hb[(size_t)(base + grow) * HID + hcol] = f2bf(hv);
          }
        }
    }
  } else {
    int j0 = blockIdx.y * 256;
    float bv[4];
#pragma unroll
    for (int n = 0; n < 4; ++n) bv[n] = bias[e * DIM + j0 + wc * 64 + n * 16 + coll];
#pragma unroll
    for (int m = 0; m < 8; ++m)
#pragma unroll
      for (int j = 0; j < 4; ++j) {
        int grow = row0 + wr * 128 + m * 16 + rowl * 4 + j;
        if (grow < cntE) {
          int tok = rows[base + grow];
          float g = rowg[base + grow];
#pragma unroll
          for (int n = 0; n < 4; ++n) {
            int col = j0 + wc * 64 + n * 16 + coll;
            atomicAdd(&out[(size_t)tok * DIM + col], g * (acc[m][n][j] + bv[n]));
          }
        }
      }
  }
}

extern "C" void kernel_launch(void* const* d_in, const int* in_sizes, int n_in,
                              void* d_out, int out_size, void* d_ws, size_t ws_size,
                              hipStream_t stream) {
  (void)in_sizes; (void)n_in; (void)out_size;
  const float* x  = (const float*)d_in[0];
  const float* Wr = (const float*)d_in[1];
  const float* W1 = (const float*)d_in[2];
  const float* b1 = (const float*)d_in[3];
  const float* W2 = (const float*)d_in[4];
  const float* b2 = (const float*)d_in[5];
  float* out = (float*)d_out;
  char* ws = (char*)d_ws;

  const size_t o_xb   = 0;
  const size_t o_w1t  = o_xb   + (size_t)N_TOK * DIM * 2;
  const size_t o_w2t  = o_w1t  + (size_t)NEXP * 2 * HID * DIM * 2;
  const size_t o_hb   = o_w2t  + (size_t)NEXP * DIM * HID * 2;
  const size_t o_rows = o_hb   + (size_t)NK * HID * 2;
  const size_t o_rowg = o_rows + (size_t)NK * 4;
  const size_t o_te   = o_rowg + (size_t)NK * 4;
  const size_t o_tg   = o_te   + (size_t)NK * 4;
  const size_t o_cnt  = o_tg   + (size_t)NK * 4;
  const size_t o_offs = o_cnt  + 64;
  const size_t o_cur  = o_offs + 64;
  const size_t o_t1   = o_cur  + 64;
  const size_t need   = o_t1   + 64;
  if (ws_size < need) return;

  unsigned short* xb  = (unsigned short*)(ws + o_xb);
  unsigned short* w1t = (unsigned short*)(ws + o_w1t);
  unsigned short* w2t = (unsigned short*)(ws + o_w2t);
  unsigned short* hb  = (unsigned short*)(ws + o_hb);
  int*   rows = (int*)(ws + o_rows);
  float* rowg = (float*)(ws + o_rowg);
  int*   te   = (int*)(ws + o_te);
  float* tg   = (float*)(ws + o_tg);
  int*   cnt  = (int*)(ws + o_cnt);
  int*   offs = (int*)(ws + o_offs);
  int*   cur  = (int*)(ws + o_cur);
  int*   tl   = (int*)(ws + o_t1);

  hipMemsetAsync(out, 0, (size_t)N_TOK * DIM * sizeof(float), stream);
  hipMemsetAsync(cnt, 0, NEXP * sizeof(int), stream);

  cvt_x_k<<<(N_TOK * DIM / 4 + 255) / 256, 256, 0, stream>>>(
      (const float4*)x, (ushort4*)xb, N_TOK * DIM / 4);
  transpose_cvt_k<<<dim3(2 * HID / 64, DIM / 64, NEXP), 256, 0, stream>>>(W1, w1t, DIM, 2 * HID);
  transpose_cvt_k<<<dim3(DIM / 64, HID / 64, NEXP), 256, 0, stream>>>(W2, w2t, HID, DIM);
  router_k<<<N_TOK / 4, 256, 0, stream>>>(x, Wr, te, tg, cnt);
  scan_k<<<1, 64, 0, stream>>>(cnt, offs, cur, tl);
  scatter_k<<<N_TOK / 256, 256, 0, stream>>>(te, tg, cur, rows, rowg);
  moe_gemm8p<0><<<dim3(MAXT2, HID / 128), 512, 0, stream>>>(
      xb, w1t, b1, hb, nullptr, rows, rowg, offs, tl);
  moe_gemm8p<1><<<dim3(MAXT2, DIM / 256), 512, 0, stream>>>(
      hb, w2t, b2, nullptr, out, rows, rowg, offs, tl);
}